// Round 2
// baseline (146.668 us; speedup 1.0000x reference)
//
#include <hip/hip_runtime.h>
#include <stdint.h>

// Kalman filter scan: B=128, T=256, V=256.
// R2 analysis: both prior kernels run ~127 us (rocprof direct) at MLP~1,
// 0.5 waves/SIMD, 8x the BW floor -- latency-bound with no TLP and the
// inline-asm pipeline defeated by the allocator (VGPR=92 < 140 needed).
//
// THIS ROUND: time-split parallelism. T=256 -> 4 segments of 64.
//   * wave 0 of each block: exact filter over steps 0..63 (P0=1000*I).
//   * waves 1..3: (a) 32-step mask-only Riccati warm-up (P forgets its
//     initial condition exponentially; from 1000*I one observation collapses
//     it; 32 steps => ~1e-8 relative error), then (b) run the segment as an
//     AFFINE MAP: given the (data-dependent) gain sequence the update is
//     x_out = A x_in + b per axis, with A shared across axes. Track (A,b)
//     instead of x.
//   * LDS handoff + 3-stage combine by wave 0 reconstructs the exact state.
// Effects: 4x occupancy (2 -> 8 waves/CU), serial depth 256 -> 96 steps,
// NO inline asm (plain loads, batched 4 steps/body, compiler-correct
// waitcnts), ~45 VGPRs.

#define KF_B 128
#define KF_T 256
#define KF_V 256
#define SEGLEN 64
#define WARM 32
#define STRIDE (KF_V * 3)   // floats per time step

// shared Riccati pieces: defines q00,q01,q11,m,is,K0,K1 and updates p00,p01,p11
#define KF_GAIN(la)                                                  \
    const float q00 = p00 + 2.f * p01 + p11 + 0.01f;                 \
    const float q01 = p01 + p11;                                     \
    const float q11 = p11 + 0.01f;                                   \
    const float m = ((la) != -1.0f) ? 1.0f : 0.0f;                   \
    const float is = m * __builtin_amdgcn_rcpf(q00 + 1.f);           \
    const float K0 = q00 * is;                                       \
    const float K1 = q01 * is;                                       \
    p00 = q00 - K0 * q00;                                            \
    p01 = q01 - K0 * q01;                                            \
    p11 = q11 - K1 * q01;

// exact step: state (x0,v0,x1,v1)
#define STEP_DIR(la, z0, z1)                                         \
    do {                                                             \
        KF_GAIN(la)                                                  \
        const float xp0 = x0 + v0;                                   \
        const float xp1 = x1 + v1;                                   \
        const float y0 = (z0) - xp0;                                 \
        const float y1 = (z1) - xp1;                                 \
        x0 = xp0 + K0 * y0;                                          \
        v0 = v0 + K1 * y0;                                           \
        x1 = xp1 + K0 * y1;                                          \
        v1 = v1 + K1 * y1;                                           \
    } while (0)

// affine step: per-step map M = [[1-K0,1-K0],[-K1,1-K1]], input m*K*z.
// A <- M*A (shared), b_axis <- M*b_axis + K*z_axis (K already masked).
#define STEP_AFF(la, z0, z1)                                         \
    do {                                                             \
        KF_GAIN(la)                                                  \
        const float s00 = a00 + a10;                                 \
        const float s01 = a01 + a11;                                 \
        a00 = s00 - K0 * s00;                                        \
        a01 = s01 - K0 * s01;                                        \
        a10 = a10 - K1 * s00;                                        \
        a11 = a11 - K1 * s01;                                        \
        const float sbx = bx0 + bx1;                                 \
        const float sby = by0 + by1;                                 \
        bx0 = sbx + K0 * ((z0) - sbx);                               \
        bx1 = bx1 + K1 * ((z0) - sbx);                               \
        by0 = sby + K0 * ((z1) - sby);                               \
        by1 = by1 + K1 * ((z1) - sby);                               \
    } while (0)

// warm-up step: Riccati only (mask from label)
#define STEP_RICC(la)                                                \
    do { KF_GAIN(la) } while (0)

__global__ __launch_bounds__(256, 4)
void kf_kernel(const float* __restrict__ batch, float* __restrict__ out) {
    const int blk = blockIdx.x;               // 512 blocks
    const int b = blk >> 2;                   // 0..127
    const int lane = threadIdx.x & 63;        // track within 64-track tile
    const int w = threadIdx.x >> 6;           // wave id = segment id 0..3
    const int v = ((blk & 3) << 6) | lane;    // 0..255

    // column base for (b, v); step t lives at col + t*STRIDE
    const float* col = batch + (size_t)b * (KF_T * STRIDE) + (size_t)v * 3;

    // handoff: per segment 1..3, per track: A(4) + bx(2) + by(2); pad to 9
    __shared__ float lds[3][64][9];

    float p00 = 1000.f, p01 = 0.f, p11 = 1000.f;
    float x0 = 0.f, v0 = 0.f, x1 = 0.f, v1 = 0.f;       // wave 0 state
    float a00 = 1.f, a01 = 0.f, a10 = 0.f, a11 = 1.f;   // waves 1..3 map
    float bx0 = 0.f, bx1 = 0.f, by0 = 0.f, by1 = 0.f;

    if (w == 0) {
        // ---- exact filter, steps 0..63 ----
        const float* p = col;
#pragma unroll 2
        for (int t = 0; t < SEGLEN; t += 4) {
            // batch the 12 loads (4 steps) ahead of the serial compute
            const float la0 = p[0],          z00 = p[1],          z01 = p[2];
            const float la1 = p[STRIDE],     z10 = p[STRIDE+1],   z11 = p[STRIDE+2];
            const float la2 = p[2*STRIDE],   z20 = p[2*STRIDE+1], z21 = p[2*STRIDE+2];
            const float la3 = p[3*STRIDE],   z30 = p[3*STRIDE+1], z31 = p[3*STRIDE+2];
            p += 4 * STRIDE;
            STEP_DIR(la0, z00, z01);
            STEP_DIR(la1, z10, z11);
            STEP_DIR(la2, z20, z21);
            STEP_DIR(la3, z30, z31);
        }
    } else {
        // ---- warm-up: mask-only Riccati over steps w*64-32 .. w*64-1 ----
        const float* p = col + (size_t)(w * SEGLEN - WARM) * STRIDE;
#pragma unroll 1
        for (int t = 0; t < WARM; t += 8) {
            const float la0 = p[0];
            const float la1 = p[STRIDE];
            const float la2 = p[2*STRIDE];
            const float la3 = p[3*STRIDE];
            const float la4 = p[4*STRIDE];
            const float la5 = p[5*STRIDE];
            const float la6 = p[6*STRIDE];
            const float la7 = p[7*STRIDE];
            p += 8 * STRIDE;
            STEP_RICC(la0); STEP_RICC(la1); STEP_RICC(la2); STEP_RICC(la3);
            STEP_RICC(la4); STEP_RICC(la5); STEP_RICC(la6); STEP_RICC(la7);
        }
        // ---- affine segment, steps w*64 .. w*64+63 ----
#pragma unroll 2
        for (int t = 0; t < SEGLEN; t += 4) {
            const float la0 = p[0],          z00 = p[1],          z01 = p[2];
            const float la1 = p[STRIDE],     z10 = p[STRIDE+1],   z11 = p[STRIDE+2];
            const float la2 = p[2*STRIDE],   z20 = p[2*STRIDE+1], z21 = p[2*STRIDE+2];
            const float la3 = p[3*STRIDE],   z30 = p[3*STRIDE+1], z31 = p[3*STRIDE+2];
            p += 4 * STRIDE;
            STEP_AFF(la0, z00, z01);
            STEP_AFF(la1, z10, z11);
            STEP_AFF(la2, z20, z21);
            STEP_AFF(la3, z30, z31);
        }
        float* q = lds[w - 1][lane];
        q[0] = a00; q[1] = a01; q[2] = a10; q[3] = a11;
        q[4] = bx0; q[5] = bx1; q[6] = by0; q[7] = by1;
    }

    __syncthreads();

    if (w == 0) {
        // ---- combine: x <- A_s x + b_s for s = 1,2,3 ----
        float X0 = x0, W0 = v0, X1 = x1, W1 = v1;
#pragma unroll
        for (int s = 0; s < 3; ++s) {
            const float* q = lds[s][lane];
            const float c00 = q[0], c01 = q[1], c10 = q[2], c11 = q[3];
            const float dx0 = q[4], dx1 = q[5], dy0 = q[6], dy1 = q[7];
            const float nX0 = c00 * X0 + c01 * W0 + dx0;
            const float nW0 = c10 * X0 + c11 * W0 + dx1;
            const float nX1 = c00 * X1 + c01 * W1 + dy0;
            const float nW1 = c10 * X1 + c11 * W1 + dy1;
            X0 = nX0; W0 = nW0; X1 = nX1; W1 = nW1;
        }
        float* o = out + ((size_t)b * KF_V + v) * 3;
        o[0] = 1.0f;
        o[1] = X0;
        o[2] = X1;
    }
}

extern "C" void kernel_launch(void* const* d_in, const int* in_sizes, int n_in,
                              void* d_out, int out_size, void* d_ws, size_t ws_size,
                              hipStream_t stream) {
    (void)in_sizes; (void)n_in; (void)d_ws; (void)ws_size; (void)out_size;
    const float* batch = (const float*)d_in[0];
    float* out = (float*)d_out;
    const int blocks = KF_B * (KF_V / 64);    // 512 blocks x 256 threads
    kf_kernel<<<blocks, 256, 0, stream>>>(batch, out);
}